// Round 1
// baseline (5710.981 us; speedup 1.0000x reference)
//
#include <hip/hip_runtime.h>
#include <stdint.h>

#define NTOK 262144
#define DIM 384
#define KC 512

constexpr int MT = 64;            // rows per block

// ---------------- async 16B global->LDS ----------------
// Dest is wave-uniform LDS base + lane*16B (HW rule, m104/m108). Our LDS layouts
// are defined so that this linear lane->16B mapping IS the layout we want; the
// transpose lives in the per-lane global source address (m173 pattern).
typedef unsigned int u32;
__device__ __forceinline__ void gload16(const float* g, float* l) {
    __builtin_amdgcn_global_load_lds(
        (__attribute__((address_space(1))) u32*)g,
        (__attribute__((address_space(3))) u32*)l, 16, 0, 0);
}

// ---------------- Kernel 1: e_sq (bit-exact numpy pairwise_sum replica) ----------------
__global__ void esq_kernel(const float* __restrict__ emb, float* __restrict__ ws) {
#pragma clang fp contract(off)
    int k = blockIdx.x * blockDim.x + threadIdx.x;
    if (k == 0) *(double*)(ws + 512) = 0.0;   // loss accumulator at byte offset 2048
    if (k < KC) {
        const float* e = emb + (size_t)k * DIM;
        float s96[4];
        for (int c = 0; c < 4; ++c) {
            const float* p = e + c * 96;
            float r[8];
#pragma unroll
            for (int j = 0; j < 8; ++j) {
                float q = p[j] * p[j];
                r[j] = q;
            }
            for (int i = 8; i < 96; i += 8) {
#pragma unroll
                for (int j = 0; j < 8; ++j) {
                    float q = p[i + j] * p[i + j];
                    r[j] = r[j] + q;
                }
            }
            s96[c] = ((r[0] + r[1]) + (r[2] + r[3])) + ((r[4] + r[5]) + (r[6] + r[7]));
        }
        ws[k] = (s96[0] + s96[1]) + (s96[2] + s96[3]);
    }
}

// ---------------- Kernel 2: fused distances + argmin + gather + loss ----------------
// dot product remains a single sequential fmaf chain over d=0..383 (ascending)
// to bit-match BLAS sgemm. LDS layouts are k-contiguous so every ds_read_b128 /
// global_load_lds maps lane->consecutive 16B (conflict-free, m134 pattern):
//   e_lds float4-slot f = j*128 + s*32 + kid   (k = kid+32j, d-sub s = (d%16)/4)
//   z_lds packed [row][16]                     (a-reads are broadcast)
__launch_bounds__(256, 2)
__global__ void vq_main(const float* __restrict__ z, const float* __restrict__ emb,
                        const float* __restrict__ ws_esq, double* __restrict__ ws_loss,
                        float* __restrict__ out_zq, float* __restrict__ out_idx) {
    __shared__ __align__(16) float z_lds[MT * 16];    // 4 KB
    __shared__ __align__(16) float e_lds[KC * 16];    // 32 KB
    __shared__ float esq_lds[KC];
    __shared__ float zsq_lds[MT];
    __shared__ unsigned long long win_lds[MT];
    __shared__ float loss_part[8];

    const int t   = threadIdx.x;
    const int kid = t & 31;        // 32 k-threads: thread's cols k = kid + 32*j
    const int mid = t >> 5;        // 8 m-groups: thread's rows r = mid*8 + mi
    const int wv  = t >> 6;        // wave id
    const int m0  = blockIdx.x * MT;

    esq_lds[t]       = ws_esq[t];
    esq_lds[t + 256] = ws_esq[t + 256];

    float acc[8][16];
#pragma unroll
    for (int a = 0; a < 8; ++a)
#pragma unroll
        for (int b = 0; b < 16; ++b) acc[a][b] = 0.f;

    float zsq_p = 0.f;

    // staging addresses (loop-invariant parts)
    // z: wave wv stages rows 16wv..16wv+15; lane l -> slot wv*64+l = (row t>>2, col4 t&3)
    const float* zsrc = z + (size_t)(m0 + (t >> 2)) * DIM + ((t & 3) << 2);
    float* zdst = z_lds + (wv << 8);
    // e: call i by wave wv covers slots f = i*256 + t .. ; from f: j=f>>7, s=(f>>5)&3, kid=f&31
    const int krow = ((t >> 7) << 5) + kid;                      // row for i=0; +64 per i
    const float* esrc = emb + (size_t)krow * DIM + (((t >> 5) & 3) << 2);
    float* edst = e_lds + (wv << 8);

    for (int dc = 0; dc < DIM; dc += 16) {
        __syncthreads();                      // previous tile fully consumed
        gload16(zsrc + dc, zdst);
#pragma unroll
        for (int i = 0; i < 8; ++i)
            gload16(esrc + dc + i * (64 * DIM), edst + (i << 10));
        __syncthreads();                      // compiler drains vmcnt before barrier

        // z_sq partials: thread owns (row t>>2, col-group t&3); fmaf chain in
        // x,y,z,w order over ascending chunks — bit-identical to prior kernel.
        {
            float4 v = *((const float4*)z_lds + t);
            zsq_p = fmaf(v.x, v.x, zsq_p);
            zsq_p = fmaf(v.y, v.y, zsq_p);
            zsq_p = fmaf(v.z, v.z, zsq_p);
            zsq_p = fmaf(v.w, v.w, zsq_p);
        }

        // GEMM inner: 8x16 per-thread outer product over d (d strictly ascending)
        const float4* z4 = (const float4*)z_lds;
        const float4* e4 = (const float4*)e_lds;
#pragma unroll
        for (int s = 0; s < 4; ++s) {
            float4 a[8];
#pragma unroll
            for (int mi = 0; mi < 8; ++mi)
                a[mi] = z4[(((mid << 3) + mi) << 2) + s];     // broadcast read
#pragma unroll
            for (int j = 0; j < 16; ++j) {
                float4 b = e4[(j << 7) + (s << 5) + kid];     // lane->contiguous 16B
#pragma unroll
                for (int mi = 0; mi < 8; ++mi) {
                    float sum = acc[mi][j];
                    sum = fmaf(a[mi].x, b.x, sum);
                    sum = fmaf(a[mi].y, b.y, sum);
                    sum = fmaf(a[mi].z, b.z, sum);
                    sum = fmaf(a[mi].w, b.w, sum);
                    acc[mi][j] = sum;
                }
            }
        }
    }

    // reduce z_sq: threads 4r..4r+3 hold the 4 col-group partials of row r;
    // combine tree (p0+p1)+(p2+p3) — bitwise identical to previous kernel.
    zsq_p += __shfl_xor(zsq_p, 1);
    zsq_p += __shfl_xor(zsq_p, 2);
    if ((t & 3) == 0) zsq_lds[t >> 2] = zsq_p;
    __syncthreads();

    // argmin per row: d = fl(fl(z_sq - 2*dot) + e_sq), first-index tie-break via packed min
    float row_loss = 0.f;
#pragma unroll
    for (int mi = 0; mi < 8; ++mi) {
        int r = mid * 8 + mi;
        float zs = zsq_lds[r];
        unsigned long long best = ~0ull;
#pragma unroll
        for (int j = 0; j < 16; ++j) {
            int k = kid + (j << 5);
            float t1 = fmaf(-2.f, acc[mi][j], zs);   // == round(zs - 2*dot), 2*dot exact
            float dist = t1 + esq_lds[k];            // second rounding, matches reference
            unsigned long long p =
                ((unsigned long long)__float_as_uint(dist) << 32) | (unsigned)k;
            best = p < best ? p : best;
        }
#pragma unroll
        for (int off = 16; off > 0; off >>= 1) {
            unsigned long long o = __shfl_xor(best, off);
            best = o < best ? o : best;
        }
        if (kid == 0) {
            win_lds[r] = best;
            out_idx[m0 + r] = (float)(unsigned)(best & 0xffffffffu);
            row_loss += __uint_as_float((unsigned)(best >> 32));  // d_min == ||z-e||^2
        }
    }
    if (kid == 0) loss_part[mid] = row_loss;
    __syncthreads();
    if (t == 0) {
        float s = 0.f;
        for (int i = 0; i < 8; ++i) s += loss_part[i];
        atomicAdd(ws_loss, (double)s);
    }

    // gather z_q = emb[best] (emb is L2-resident), coalesced 32-lane row copies
#pragma unroll
    for (int p = 0; p < 8; ++p) {
        int r = (p << 3) + mid;
        unsigned idx = (unsigned)(win_lds[r] & 0xffffffffu);
        const float* er = emb + (size_t)idx * DIM;
        float* orow = out_zq + (size_t)(m0 + r) * DIM;
        for (int c = kid * 4; c < DIM; c += 128)
            *(float4*)(orow + c) = *(const float4*)(er + c);
    }
}

// ---------------- Kernel 3: finalize loss ----------------
__global__ void finalize_kernel(const double* __restrict__ ws_loss, float* __restrict__ out_loss) {
    if (threadIdx.x == 0 && blockIdx.x == 0) {
        double s = *ws_loss;
        *out_loss = (float)(1.25 * s / (double)((size_t)NTOK * DIM));
    }
}

extern "C" void kernel_launch(void* const* d_in, const int* in_sizes, int n_in,
                              void* d_out, int out_size, void* d_ws, size_t ws_size,
                              hipStream_t stream) {
    const float* z   = (const float*)d_in[0];
    const float* emb = (const float*)d_in[1];
    float* out     = (float*)d_out;
    float* ws      = (float*)d_ws;
    float* out_zq  = out;
    float* out_idx = out + (size_t)NTOK * DIM;
    float* out_ls  = out + (size_t)NTOK * DIM + NTOK;

    esq_kernel<<<2, 256, 0, stream>>>(emb, ws);
    vq_main<<<NTOK / MT, 256, 0, stream>>>(z, emb, ws, (double*)(ws + 512), out_zq, out_idx);
    finalize_kernel<<<1, 1, 0, stream>>>((const double*)(ws + 512), out_ls);
}

// Round 2
// 1876.480 us; speedup vs baseline: 3.0435x; 3.0435x over previous
//
#include <hip/hip_runtime.h>
#include <stdint.h>

#define NTOK 262144
#define DIM 384
#define KC 512

constexpr int MT = 64;            // rows per block

// ---------------- Kernel 1: e_sq (bit-exact numpy pairwise_sum replica) ----------------
__global__ void esq_kernel(const float* __restrict__ emb, float* __restrict__ ws) {
#pragma clang fp contract(off)
    int k = blockIdx.x * blockDim.x + threadIdx.x;
    if (k == 0) *(double*)(ws + 512) = 0.0;   // loss accumulator at byte offset 2048
    if (k < KC) {
        const float* e = emb + (size_t)k * DIM;
        float s96[4];
        for (int c = 0; c < 4; ++c) {
            const float* p = e + c * 96;
            float r[8];
#pragma unroll
            for (int j = 0; j < 8; ++j) {
                float q = p[j] * p[j];
                r[j] = q;
            }
            for (int i = 8; i < 96; i += 8) {
#pragma unroll
                for (int j = 0; j < 8; ++j) {
                    float q = p[i + j] * p[i + j];
                    r[j] = r[j] + q;
                }
            }
            s96[c] = ((r[0] + r[1]) + (r[2] + r[3])) + ((r[4] + r[5]) + (r[6] + r[7]));
        }
        ws[k] = (s96[0] + s96[1]) + (s96[2] + s96[3]);
    }
}

// ---------------- Kernel 2: fused distances + argmin + gather + loss ----------------
// dot product remains a single sequential fmaf chain over d=0..383 (ascending)
// to bit-match BLAS sgemm. LDS layouts are k-contiguous so every LDS access is
// conflict-free (verified 0 conflicts in the previous round with this layout):
//   e_lds float4-slot f = j*128 + s*32 + kid   (k = kid+32j, d-sub s = (d%16)/4)
//   z_lds packed [row][16]                     (a-reads are 2-address broadcasts)
// Staging is REG-staged (global->reg->ds_write): the global_load_lds variant
// spilled the 128-VGPR accumulator to scratch (9.2 GB scratch writes).
__launch_bounds__(256, 2)
__global__ void vq_main(const float* __restrict__ z, const float* __restrict__ emb,
                        const float* __restrict__ ws_esq, double* __restrict__ ws_loss,
                        float* __restrict__ out_zq, float* __restrict__ out_idx) {
    __shared__ __align__(16) float z_lds[MT * 16];    // 4 KB
    __shared__ __align__(16) float e_lds[KC * 16];    // 32 KB
    __shared__ float esq_lds[KC];
    __shared__ float zsq_lds[MT];
    __shared__ unsigned long long win_lds[MT];
    __shared__ float loss_part[8];

    const int t   = threadIdx.x;
    const int kid = t & 31;        // 32 k-threads: thread's cols k = kid + 32*j
    const int mid = t >> 5;        // 8 m-groups: thread's rows r = mid*8 + mi
    const int m0  = blockIdx.x * MT;

    esq_lds[t]       = ws_esq[t];
    esq_lds[t + 256] = ws_esq[t + 256];

    float acc[8][16];
#pragma unroll
    for (int a = 0; a < 8; ++a)
#pragma unroll
        for (int b = 0; b < 16; ++b) acc[a][b] = 0.f;

    float zsq_p = 0.f;

    // staging geometry: thread t stages row sr = t>>2, float4-col s = t&3
    const int sr = t >> 2;
    const float* zsrc = z + (size_t)(m0 + sr) * DIM + ((t & 3) << 2);
    // e rows k = sr + 64*i; LDS slot f = i*256 + (sr>>5)*128 + (t&3)*32 + (sr&31)
    //   (t>>7 == sr>>5). Per-i stride is 256 slots = 4096 B -> ds offset imm.
    const float* esrc = emb + (size_t)sr * DIM + ((t & 3) << 2);
    float4* e4w = (float4*)e_lds + ((t >> 7) << 7) + ((t & 3) << 5) + (sr & 31);

    for (int dc = 0; dc < DIM; dc += 16) {
        __syncthreads();                      // previous tile fully consumed
        // stage z tile: slot t (linear across lanes -> conflict-free write)
        {
            float4 v = *(const float4*)(zsrc + dc);
            ((float4*)z_lds)[t] = v;
        }
        // stage e tile: 8 rows per thread, bank-even writes (each bank 8 touches/wave)
#pragma unroll
        for (int i = 0; i < 8; ++i) {
            float4 v = *(const float4*)(esrc + dc + (size_t)i * (64 * DIM));
            e4w[i << 8] = v;
        }
        __syncthreads();

        // z_sq partials: thread owns (row t>>2, col-group t&3); fmaf chain in
        // x,y,z,w order over ascending chunks — bit-identical to prior rounds.
        {
            float4 v = *((const float4*)z_lds + t);
            zsq_p = fmaf(v.x, v.x, zsq_p);
            zsq_p = fmaf(v.y, v.y, zsq_p);
            zsq_p = fmaf(v.z, v.z, zsq_p);
            zsq_p = fmaf(v.w, v.w, zsq_p);
        }

        // GEMM inner: 8x16 per-thread outer product over d (d strictly ascending)
        const float4* z4 = (const float4*)z_lds;
        const float4* e4 = (const float4*)e_lds;
#pragma unroll
        for (int s = 0; s < 4; ++s) {
            float4 a[8];
#pragma unroll
            for (int mi = 0; mi < 8; ++mi)
                a[mi] = z4[(((mid << 3) + mi) << 2) + s];     // 2-address broadcast
#pragma unroll
            for (int j = 0; j < 16; ++j) {
                float4 b = e4[(j << 7) + (s << 5) + kid];     // lane->contiguous 16B
#pragma unroll
                for (int mi = 0; mi < 8; ++mi) {
                    float sum = acc[mi][j];
                    sum = fmaf(a[mi].x, b.x, sum);
                    sum = fmaf(a[mi].y, b.y, sum);
                    sum = fmaf(a[mi].z, b.z, sum);
                    sum = fmaf(a[mi].w, b.w, sum);
                    acc[mi][j] = sum;
                }
            }
        }
    }

    // reduce z_sq: threads 4r..4r+3 hold the 4 col-group partials of row r;
    // combine tree (p0+p1)+(p2+p3) — bitwise identical to previous rounds.
    zsq_p += __shfl_xor(zsq_p, 1);
    zsq_p += __shfl_xor(zsq_p, 2);
    if ((t & 3) == 0) zsq_lds[t >> 2] = zsq_p;
    __syncthreads();

    // argmin per row: d = fl(fl(z_sq - 2*dot) + e_sq), first-index tie-break via packed min
    float row_loss = 0.f;
#pragma unroll
    for (int mi = 0; mi < 8; ++mi) {
        int r = mid * 8 + mi;
        float zs = zsq_lds[r];
        unsigned long long best = ~0ull;
#pragma unroll
        for (int j = 0; j < 16; ++j) {
            int k = kid + (j << 5);
            float t1 = fmaf(-2.f, acc[mi][j], zs);   // == round(zs - 2*dot), 2*dot exact
            float dist = t1 + esq_lds[k];            // second rounding, matches reference
            unsigned long long p =
                ((unsigned long long)__float_as_uint(dist) << 32) | (unsigned)k;
            best = p < best ? p : best;
        }
#pragma unroll
        for (int off = 16; off > 0; off >>= 1) {
            unsigned long long o = __shfl_xor(best, off);
            best = o < best ? o : best;
        }
        if (kid == 0) {
            win_lds[r] = best;
            out_idx[m0 + r] = (float)(unsigned)(best & 0xffffffffu);
            row_loss += __uint_as_float((unsigned)(best >> 32));  // d_min == ||z-e||^2
        }
    }
    if (kid == 0) loss_part[mid] = row_loss;
    __syncthreads();
    if (t == 0) {
        float s = 0.f;
        for (int i = 0; i < 8; ++i) s += loss_part[i];
        atomicAdd(ws_loss, (double)s);
    }

    // gather z_q = emb[best] (emb is L2-resident), coalesced 32-lane row copies
#pragma unroll
    for (int p = 0; p < 8; ++p) {
        int r = (p << 3) + mid;
        unsigned idx = (unsigned)(win_lds[r] & 0xffffffffu);
        const float* er = emb + (size_t)idx * DIM;
        float* orow = out_zq + (size_t)(m0 + r) * DIM;
        for (int c = kid * 4; c < DIM; c += 128)
            *(float4*)(orow + c) = *(const float4*)(er + c);
    }
}

// ---------------- Kernel 3: finalize loss ----------------
__global__ void finalize_kernel(const double* __restrict__ ws_loss, float* __restrict__ out_loss) {
    if (threadIdx.x == 0 && blockIdx.x == 0) {
        double s = *ws_loss;
        *out_loss = (float)(1.25 * s / (double)((size_t)NTOK * DIM));
    }
}

extern "C" void kernel_launch(void* const* d_in, const int* in_sizes, int n_in,
                              void* d_out, int out_size, void* d_ws, size_t ws_size,
                              hipStream_t stream) {
    const float* z   = (const float*)d_in[0];
    const float* emb = (const float*)d_in[1];
    float* out     = (float*)d_out;
    float* ws      = (float*)d_ws;
    float* out_zq  = out;
    float* out_idx = out + (size_t)NTOK * DIM;
    float* out_ls  = out + (size_t)NTOK * DIM + NTOK;

    esq_kernel<<<2, 256, 0, stream>>>(emb, ws);
    vq_main<<<NTOK / MT, 256, 0, stream>>>(z, emb, ws, (double*)(ws + 512), out_zq, out_idx);
    finalize_kernel<<<1, 1, 0, stream>>>((const double*)(ws + 512), out_ls);
}